// Round 9
// baseline (209.707 us; speedup 1.0000x reference)
//
#include <hip/hip_runtime.h>
#include <hip/hip_bf16.h>

typedef __hip_bfloat16 bf16;
typedef unsigned short u16t;
typedef unsigned int u32t;
typedef __attribute__((ext_vector_type(8))) short bf16x8_t;
typedef __attribute__((ext_vector_type(4))) float f32x4_t;

#define DEVI static __device__ __forceinline__

DEVI float u2f(u32t bits) { union { u32t u; float f; } v; v.u = bits; return v.f; }
DEVI float bflo(u32t u) { return u2f((u & 0xffffu) << 16); }
DEVI float bfhi(u32t u) { return u2f(u & 0xffff0000u); }
DEVI float sh2f(short s) { return u2f(((u32t)(u16t)s) << 16); }
DEVI float bf2f(bf16 h) { return __bfloat162float(h); }
DEVI bf16 f2bf(float f) { return __float2bfloat16(f); }
DEVI u16t f2bfbits(float f) {
  bf16 h = __float2bfloat16(f);
  union { bf16 h; u16t u; } v; v.h = h; return v.u;
}

// async global->LDS, 16B per lane. LDS dest must be wave-uniform base + lane*16.
DEVI void gl_lds16(const void* g, void* l) {
  __builtin_amdgcn_global_load_lds(
      (const __attribute__((address_space(1))) unsigned int*)g,
      (__attribute__((address_space(3))) unsigned int*)l, 16, 0, 0);
}

// Problem constants: x (2,8,56,56,128); windows (2,7,7) -> N=98; NW=512
#define TOK   50176
#define NWIN  512
#define NTOK  98
#define NHEAD 4
#define HDIM  32
#define QSCALE 0.17677669529663687f

// ---------------------------------------------------------------------------
// Merged setup kernel: blocks [0,768) convert weights fp32->bf16 (q-rows
// pre-scaled); blocks [768,806) build BmatT + scaled qkv bias.
// ---------------------------------------------------------------------------
__global__ __launch_bounds__(256) void setup_k(
    const float* __restrict__ a, const float* __restrict__ b,
    const float* __restrict__ c, const float* __restrict__ d,
    bf16* __restrict__ o,
    const float* __restrict__ btab, const int* __restrict__ relidx,
    const float* __restrict__ qkv_b, float* __restrict__ BmatT,
    float* __restrict__ bsc) {
  int bx = blockIdx.x;
  if (bx < 768) {
    int i = bx * 256 + threadIdx.x;
    const float* s; int off;
    if (i < 49152)       { s = a; off = 0; }
    else if (i < 65536)  { s = b; off = 49152; }
    else if (i < 131072) { s = c; off = 65536; }
    else                 { s = d; off = 131072; }
    float v = s[i - off];
    if (i < 16384) v *= QSCALE;     // q-slice of qkv_w
    o[i] = f2bf(v);
  } else {
    int idx = (bx - 768) * 256 + threadIdx.x;
    if (idx < NTOK * NTOK) {
      int i = idx / NTOK, j = idx - i * NTOK;
      int r = relidx[idx] * NHEAD;
#pragma unroll
      for (int h = 0; h < NHEAD; h++)
        BmatT[(size_t)(h * NTOK + j) * 112 + i] = btab[r + h];
    }
    if (bx == 768 && threadIdx.x < 384)
      bsc[threadIdx.x] = qkv_b[threadIdx.x] * (threadIdx.x < 128 ? QSCALE : 1.0f);
  }
}

// window-reverse: grow = nw*98+n -> token index
DEVI int winrev(int grow) {
  int nw = grow / NTOK, n = grow - nw * NTOK;
  int wq = nw & 7, hq = (nw >> 3) & 7, dq = (nw >> 6) & 3, bb = nw >> 8;
  int wr = n % 7; int q7 = n / 7; int hr = q7 % 7, dr = q7 / 7;
  return ((bb * 8 + dq * 2 + dr) * 56 + hq * 7 + hr) * 56 + wq * 7 + wr;
}

// ---------------------------------------------------------------------------
// Fused LN1 + window partition + QKV GEMM.
// One block per 64 window-rows (784 blocks). LDS 48KB -> 3 blocks/CU.
// ---------------------------------------------------------------------------
__global__ __launch_bounds__(256) void qkvln_k(
    const float* __restrict__ x, const float* __restrict__ n1w,
    const float* __restrict__ n1b, const bf16* __restrict__ W,
    const float* __restrict__ bsc, bf16* __restrict__ qkvO)
{
  __shared__ __align__(16) short As[64 * 128];    // 16KB LN1'd A tile (swz)
  __shared__ __align__(16) short Bs[128 * 128];   // 32KB weights / C staging
  const int tid = threadIdx.x;
  const int rowBase = blockIdx.x << 6;
  const int wv = tid >> 6, lane = tid & 63;
  const int q = lane >> 4, r16 = lane & 15;

  // stage weight chunk 0 (async DMA overlaps LN compute below)
#pragma unroll
  for (int t = 0; t < 8; t++) {
    int f = tid + (t << 8);
    int row = f >> 4, cs = (f & 15) ^ (row & 15);
    gl_lds16((const u16t*)W + (size_t)row * 128 + (cs << 3), &Bs[f << 3]);
  }

  // LN1 + window partition into As (bit-identical arithmetic to ln1_k)
  {
    const int c = lane << 1;
    float lw0 = n1w[c], lw1 = n1w[c + 1];
    float lb0 = n1b[c], lb1 = n1b[c + 1];
#pragma unroll
    for (int rr = 0; rr < 16; rr++) {
      int row = (wv << 4) + rr;
      int tt = winrev(rowBase + row);
      float2 xv = *(const float2*)(x + (size_t)tt * 128 + c);
      float x0 = xv.x, x1 = xv.y;
      float s = x0 + x1, ss = x0 * x0 + x1 * x1;
#pragma unroll
      for (int m = 32; m; m >>= 1) { s += __shfl_xor(s, m); ss += __shfl_xor(ss, m); }
      float mean = s * 0.0078125f;
      float var = ss * 0.0078125f - mean * mean;
      float rstd = rsqrtf(var + 1e-5f);
      float y0 = (x0 - mean) * rstd * lw0 + lb0;
      float y1 = (x1 - mean) * rstd * lw1 + lb1;
      u32t ov = ((u32t)f2bfbits(y1) << 16) | (u32t)f2bfbits(y0);
      int slot = (lane >> 2) ^ (row & 15);
      *(u32t*)&As[(row << 7) + (slot << 3) + ((lane & 3) << 1)] = ov;
    }
  }
  __syncthreads();

#pragma unroll 1
  for (int qt = 0; qt < 3; qt++) {
    if (qt > 0) {
#pragma unroll
      for (int t = 0; t < 8; t++) {
        int f = tid + (t << 8);
        int row = f >> 4, cs = (f & 15) ^ (row & 15);
        gl_lds16((const u16t*)W + (size_t)((qt << 7) + row) * 128 + (cs << 3),
                 &Bs[f << 3]);
      }
      __syncthreads();
    }
    f32x4_t acc[8];
#pragma unroll
    for (int j = 0; j < 8; j++) acc[j] = (f32x4_t){0.f, 0.f, 0.f, 0.f};
#pragma unroll
    for (int ks = 0; ks < 4; ks++) {
      int rowA = (wv << 4) + r16;
      int slotA = ((ks << 2) + q) ^ (rowA & 15);
      bf16x8_t af = *(const bf16x8_t*)&As[(rowA << 7) + (slotA << 3)];
      bf16x8_t bfr[8];
#pragma unroll
      for (int nt = 0; nt < 8; nt++) {
        int row = (nt << 4) + r16;
        int slot = ((ks << 2) + q) ^ (row & 15);
        bfr[nt] = *(const bf16x8_t*)&Bs[(row << 7) + (slot << 3)];
      }
#pragma unroll
      for (int nt = 0; nt < 8; nt++)
        acc[nt] = __builtin_amdgcn_mfma_f32_16x16x32_bf16(af, bfr[nt], acc[nt], 0, 0, 0);
    }
    float bv[8];
#pragma unroll
    for (int nt = 0; nt < 8; nt++) bv[nt] = bsc[(qt << 7) + (nt << 4) + r16];
    __syncthreads();   // MFMA Bs reads done before overwrite
    // C + bias -> Bs bf16 (64 rows x 128 cols)
#pragma unroll
    for (int reg = 0; reg < 4; reg++) {
      int lrow = (wv << 4) + (q << 2) + reg;
#pragma unroll
      for (int nt = 0; nt < 8; nt++)
        Bs[(lrow << 7) + (nt << 4) + r16] = (short)f2bfbits(acc[nt][reg] + bv[nt]);
    }
    __syncthreads();
    // coalesced uint4 out
#pragma unroll
    for (int t = 0; t < 4; t++) {
      int f = tid + (t << 8);
      int row = f >> 4, c8 = (f & 15) << 3;
      size_t ob = (size_t)(rowBase + row) * 384 + (qt << 7) + c8;
      *(uint4*)((u16t*)qkvO + ob) = *(const uint4*)&Bs[(row << 7) + c8];
    }
    if (qt < 2) __syncthreads();   // out reads done before next chunk staging
  }
}

// ---------------------------------------------------------------------------
// Fused proj + residual + LN2 + MLP + final residual, one block per 128
// window-rows (392 blocks). x2 and xn2 never touch HBM:
//   proj GEMM -> C+bias -> x2 (kept in 16 VGPRs, epilogue layout, AND in LDS)
//   -> LN2 writes xn2 directly into the swizzled A layout in LDS
//   -> 8-chunk MLP loop (fc1+GELU+fc2) -> out = Cf + x2(regs), winrev store.
// Saves 51.4MB HBM (x2/xn2 round-trips) + one launch/tail vs split kernels.
// LDS 80KB -> 2 blocks/CU x 8 waves = 4 waves/SIMD (proven-good regime).
// Bit-identical arithmetic to round-7 proj_k + mlp_fused_k.
// ---------------------------------------------------------------------------
__global__ __launch_bounds__(512, 4) void projmlp_k(
    const bf16* __restrict__ A, const bf16* __restrict__ Wp,
    const float* __restrict__ pb, const float* __restrict__ resX,
    const float* __restrict__ lnw, const float* __restrict__ lnb,
    const bf16* __restrict__ F1, const bf16* __restrict__ F2,
    const float* __restrict__ b1, const float* __restrict__ b2,
    float* __restrict__ out)
{
  __shared__ __align__(16) char smem[81920];
  short* As  = (short*)smem;             // 32K: attn tile -> C -> x2 -> xn2(swz)
  short* Bs  = (short*)(smem + 32768);   // 32K: proj weights (proj phase)
  short* F1s = (short*)(smem + 32768);   // 16K: fc1 chunk (MLP phase)
  short* F2s = (short*)(smem + 49152);   // 16K: fc2 chunk
  short* Hs  = (short*)(smem + 65536);   // 16K: H chunk
  float* Cf  = (float*)smem;             // [128][132] fp32 epilogue (67.5KB)

  const int tid = threadIdx.x;
  const int rowBase = blockIdx.x << 7;
  const int wv = tid >> 6, lane = tid & 63;
  const int q = lane >> 4, r16 = lane & 15;
  const int mB = wv << 4;                // one 16-row m-tile per wave

  // ---- proj phase: stage attn tile (A) + proj weights (Bs) ----
#pragma unroll
  for (int t = 0; t < 4; t++) {
    int f = tid + (t << 9);
    int row = f >> 4, cs = (f & 15) ^ (row & 15);
    gl_lds16((const u16t*)A + (size_t)(rowBase + row) * 128 + (cs << 3),
             &As[f << 3]);
  }
#pragma unroll
  for (int t = 0; t < 4; t++) {
    int f = tid + (t << 9);
    int row = f >> 4, cs = (f & 15) ^ (row & 15);
    gl_lds16((const u16t*)Wp + (size_t)row * 128 + (cs << 3), &Bs[f << 3]);
  }
  __syncthreads();

  f32x4_t acc[8];
#pragma unroll
  for (int j = 0; j < 8; j++) acc[j] = (f32x4_t){0.f, 0.f, 0.f, 0.f};
#pragma unroll
  for (int ks = 0; ks < 4; ks++) {
    int rowA = mB + r16;
    int slotA = ((ks << 2) + q) ^ (rowA & 15);
    bf16x8_t af = *(const bf16x8_t*)&As[(rowA << 7) + (slotA << 3)];
    bf16x8_t bfr[8];
#pragma unroll
    for (int nt = 0; nt < 8; nt++) {
      int row = (nt << 4) + r16;
      int slot = ((ks << 2) + q) ^ (row & 15);
      bfr[nt] = *(const bf16x8_t*)&Bs[(row << 7) + (slot << 3)];
    }
#pragma unroll
    for (int nt = 0; nt < 8; nt++)
      acc[nt] = __builtin_amdgcn_mfma_f32_16x16x32_bf16(af, bfr[nt], acc[nt], 0, 0, 0);
  }
  __syncthreads();   // Bs reads done -> safe to overwrite with F1/F2 chunk 0

  // prefetch MLP weight chunk 0 (DMA overlaps proj epilogue VALU)
#pragma unroll
  for (int t = 0; t < 2; t++) {
    int f = tid + (t << 9);
    int row = f >> 4, cs = (f & 15) ^ (row & 15);
    gl_lds16((const u16t*)F1 + (size_t)row * 128 + (cs << 3), &F1s[f << 3]);
  }
#pragma unroll
  for (int t = 0; t < 2; t++) {
    int f = tid + (t << 9);
    int row = f >> 3, cs = (f & 7) ^ (row & 7);
    gl_lds16((const u16t*)F2 + (size_t)row * 512 + (cs << 3), &F2s[f << 3]);
  }

  // C + bias -> As bf16 (linear stride 128, own rows)
  float pbv[8];
#pragma unroll
  for (int nt = 0; nt < 8; nt++) pbv[nt] = pb[(nt << 4) + r16];
#pragma unroll
  for (int reg = 0; reg < 4; reg++) {
    int lrow = mB + (q << 2) + reg;
#pragma unroll
    for (int nt = 0; nt < 8; nt++)
      As[(lrow << 7) + (nt << 4) + r16] = (short)f2bfbits(acc[nt][reg] + pbv[nt]);
  }
  __syncthreads();

  // residual (token-addressed x read): x2 -> LDS (linear) + 16 VGPRs
  // (epilogue layout: thread t-th iter owns channels c4..c4+3 of row f>>5)
  u32t x2r[16];
#pragma unroll
  for (int t = 0; t < 8; t++) {
    int f = tid + (t << 9);
    int row = f >> 5, c4 = (f & 31) << 2;
    int tt = winrev(rowBase + row);
    size_t ob = (size_t)tt * 128 + c4;
    float4 r0 = *(const float4*)(resX + ob);
    short* cs = &As[(row << 7) + c4];
    u16t pk[4];
    pk[0] = f2bfbits(sh2f(cs[0]) + r0.x);
    pk[1] = f2bfbits(sh2f(cs[1]) + r0.y);
    pk[2] = f2bfbits(sh2f(cs[2]) + r0.z);
    pk[3] = f2bfbits(sh2f(cs[3]) + r0.w);
    u32t lo = ((u32t)pk[1] << 16) | pk[0];
    u32t hi = ((u32t)pk[3] << 16) | pk[2];
    x2r[2 * t] = lo; x2r[2 * t + 1] = hi;
    uint2 wvv; wvv.x = lo; wvv.y = hi;
    *(uint2*)cs = wvv;
  }
  __syncthreads();

  // LN2: own 16 rows, read x2 linear, write xn2 swizzled (in-wave safe:
  // full row read by the wave before any write)
  {
    const int c = lane << 1;
    float2 lw = *(const float2*)(lnw + c);
    float2 lb = *(const float2*)(lnb + c);
#pragma unroll 4
    for (int rr = 0; rr < 16; rr++) {
      int row = (wv << 4) + rr;
      u32t u = *(const u32t*)&As[(row << 7) + c];
      float x0 = bflo(u), x1 = bfhi(u);
      float s = x0 + x1, ss = x0 * x0 + x1 * x1;
#pragma unroll
      for (int m = 32; m; m >>= 1) { s += __shfl_xor(s, m); ss += __shfl_xor(ss, m); }
      float mean = s * 0.0078125f;
      float var = ss * 0.0078125f - mean * mean;
      float rstd = rsqrtf(var + 1e-5f);
      float y0 = (x0 - mean) * rstd * lw.x + lb.x;
      float y1 = (x1 - mean) * rstd * lw.y + lb.y;
      u32t ov = ((u32t)f2bfbits(y1) << 16) | (u32t)f2bfbits(y0);
      int slot = (lane >> 2) ^ (row & 15);
      *(u32t*)&As[(row << 7) + (slot << 3) + ((lane & 3) << 1)] = ov;
    }
  }
  __syncthreads();   // xn2 visible + F1/F2 chunk-0 DMA drained

  // ---- MLP phase (identical structure to mlp_fused_k) ----
  f32x4_t oacc[8];
#pragma unroll
  for (int j = 0; j < 8; j++) oacc[j] = (f32x4_t){0.f, 0.f, 0.f, 0.f};

#pragma unroll 1
  for (int c = 0; c < 8; c++) {
    if (c > 0) {
#pragma unroll
      for (int t = 0; t < 2; t++) {
        int f = tid + (t << 9);
        int row = f >> 4, cs = (f & 15) ^ (row & 15);
        gl_lds16((const u16t*)F1 + (size_t)(c * 64 + row) * 128 + (cs << 3),
                 &F1s[f << 3]);
      }
#pragma unroll
      for (int t = 0; t < 2; t++) {
        int f = tid + (t << 9);
        int row = f >> 3, cs = (f & 7) ^ (row & 7);
        gl_lds16((const u16t*)F2 + (size_t)row * 512 + c * 64 + (cs << 3),
                 &F2s[f << 3]);
      }
      __syncthreads();
    }

    // fc1: H-chunk rows mB..mB+15 (K=128, 4 ks; 16 MFMA/wave)
    f32x4_t hacc[4];
#pragma unroll
    for (int j = 0; j < 4; j++) hacc[j] = (f32x4_t){0.f, 0.f, 0.f, 0.f};
#pragma unroll
    for (int ks = 0; ks < 4; ks++) {
      int rowA = mB + r16;
      int slotA = ((ks << 2) + q) ^ (rowA & 15);
      bf16x8_t af = *(const bf16x8_t*)&As[(rowA << 7) + (slotA << 3)];
      bf16x8_t bfr[4];
#pragma unroll
      for (int nt = 0; nt < 4; nt++) {
        int row = (nt << 4) + r16;
        int slot = ((ks << 2) + q) ^ (row & 15);
        bfr[nt] = *(const bf16x8_t*)&F1s[(row << 7) + (slot << 3)];
      }
#pragma unroll
      for (int nt = 0; nt < 4; nt++)
        hacc[nt] = __builtin_amdgcn_mfma_f32_16x16x32_bf16(af, bfr[nt], hacc[nt], 0, 0, 0);
    }

    // bias + GELU -> Hs bf16 (8-short-slot XOR swizzle on row&7)
    float bb[4];
#pragma unroll
    for (int nt = 0; nt < 4; nt++) bb[nt] = b1[c * 64 + (nt << 4) + r16];
#pragma unroll
    for (int reg = 0; reg < 4; reg++) {
      int lrow = mB + (q << 2) + reg;
#pragma unroll
      for (int nt = 0; nt < 4; nt++) {
        float v = hacc[nt][reg] + bb[nt];
        v = 0.5f * v * (1.0f + erff(v * 0.70710678118654752f));
        int col = (nt << 4) + r16;
        int sp = (col >> 3) ^ (lrow & 7);
        Hs[(lrow << 6) + (sp << 3) + (col & 7)] = (short)f2bfbits(v);
      }
    }
    __syncthreads();

    // fc2: out += Hc @ F2c^T  (K=64, 2 ks; 16 MFMA/wave)
#pragma unroll
    for (int ks = 0; ks < 2; ks++) {
      int rowA = mB + r16;
      int slotA = ((ks << 2) + q) ^ (rowA & 7);
      bf16x8_t af = *(const bf16x8_t*)&Hs[(rowA << 6) + (slotA << 3)];
      bf16x8_t bfr[8];
#pragma unroll
      for (int nt = 0; nt < 8; nt++) {
        int row = (nt << 4) + r16;
        int slot = ((ks << 2) + q) ^ (row & 7);
        bfr[nt] = *(const bf16x8_t*)&F2s[(row << 6) + (slot << 3)];
      }
#pragma unroll
      for (int nt = 0; nt < 8; nt++)
        oacc[nt] = __builtin_amdgcn_mfma_f32_16x16x32_bf16(af, bfr[nt], oacc[nt], 0, 0, 0);
    }
    __syncthreads();   // guards next chunk's weight staging / Hs reuse
  }

  // epilogue: Cf = oacc + b2 (stride 132), out = Cf + x2(regs), winrev store
  float bv[8];
#pragma unroll
  for (int nt = 0; nt < 8; nt++) bv[nt] = b2[(nt << 4) + r16];
#pragma unroll
  for (int reg = 0; reg < 4; reg++) {
    int lrow = mB + (q << 2) + reg;
#pragma unroll
    for (int nt = 0; nt < 8; nt++)
      Cf[lrow * 132 + (nt << 4) + r16] = oacc[nt][reg] + bv[nt];
  }
  __syncthreads();
#pragma unroll
  for (int t = 0; t < 8; t++) {
    int f = tid + (t << 9);
    int row = f >> 5, c4 = (f & 31) << 2;
    int tt = winrev(rowBase + row);
    size_t ob = (size_t)tt * 128 + c4;
    const float* cp = &Cf[row * 132 + c4];
    u32t lo = x2r[2 * t], hi = x2r[2 * t + 1];
    float4 v;
    v.x = cp[0] + bflo(lo);
    v.y = cp[1] + bfhi(lo);
    v.z = cp[2] + bflo(hi);
    v.w = cp[3] + bfhi(hi);
    *(float4*)(out + ob) = v;
  }
}

// ---------------------------------------------------------------------------
// MFMA windowed attention (verified round-1 structure; bias pre-loaded into
// the QK accumulator in C-layout; q pre-scaled at weight conversion).
// ---------------------------------------------------------------------------
#define PSTR 136
__global__ __launch_bounds__(256) void attn_mfma_k(
    const bf16* __restrict__ qkv, const float* __restrict__ BmatT,
    bf16* __restrict__ out)
{
  __shared__ short Vt[32 * PSTR];    // V^T [d][j], zero-padded j>=98
  __shared__ short Ps[112 * PSTR];   // P [i][j] bf16, cols 112..135 zeroed
  const int nw = blockIdx.x, h = blockIdx.y;
  const int tid = threadIdx.x;
  const int wv = tid >> 6, lane = tid & 63;
  const int q = lane >> 4, r16 = lane & 15;

  for (int idx = tid; idx < 32 * 38; idx += 256) {
    int d = idx / 38, j = 98 + idx % 38;
    Vt[d * PSTR + j] = 0;
  }
  for (int idx = tid; idx < 112 * 12; idx += 256) {
    int r = idx / 12, c = (idx % 12) << 1;
    *(u32t*)&Ps[r * PSTR + 112 + c] = 0;
  }
  for (int idx = tid; idx < NTOK * 16; idx += 256) {
    int j = idx >> 4, d2 = (idx & 15) << 1;
    u32t uv = *(const u32t*)((const u16t*)qkv +
                             (size_t)(nw * NTOK + j) * 384 + 256 + h * 32 + d2);
    Vt[d2 * PSTR + j] = (short)(uv & 0xffffu);
    Vt[(d2 + 1) * PSTR + j] = (short)(uv >> 16);
  }
  __syncthreads();

  const int mt0 = wv;
  const bool has2 = (wv + 4) < 7;
  const int mt1 = has2 ? wv + 4 : wv;

  int i0 = mt0 * 16 + r16; if (i0 > NTOK - 1) i0 = NTOK - 1;
  int i1 = mt1 * 16 + r16; if (i1 > NTOK - 1) i1 = NTOK - 1;
  bf16x8_t aq0 = *(const bf16x8_t*)((const u16t*)qkv +
      (size_t)(nw * NTOK + i0) * 384 + h * 32 + (q << 3));
  bf16x8_t aq1 = *(const bf16x8_t*)((const u16t*)qkv +
      (size_t)(nw * NTOK + i1) * 384 + h * 32 + (q << 3));

  f32x4_t sc[2][7];
#pragma unroll
  for (int nt = 0; nt < 7; nt++) {
    int j = (nt << 4) + r16; if (j > NTOK - 1) j = NTOK - 1;
    const float* bRow = &BmatT[(size_t)(h * NTOK + j) * 112];
    bf16x8_t bk = *(const bf16x8_t*)((const u16t*)qkv +
        (size_t)(nw * NTOK + j) * 384 + 128 + h * 32 + (q << 3));
    f32x4_t b0 = *(const f32x4_t*)&bRow[mt0 * 16 + (q << 2)];
    f32x4_t b1 = *(const f32x4_t*)&bRow[mt1 * 16 + (q << 2)];
    sc[0][nt] = __builtin_amdgcn_mfma_f32_16x16x32_bf16(aq0, bk, b0, 0, 0, 0);
    sc[1][nt] = __builtin_amdgcn_mfma_f32_16x16x32_bf16(aq1, bk, b1, 0, 0, 0);
  }

#pragma unroll
  for (int sel = 0; sel < 2; sel++) {
    if (sel == 1 && !has2) break;
    int mtile = sel ? mt1 : mt0;
    int ibase = mtile * 16 + (q << 2);
    float s[4][7];
#pragma unroll
    for (int nt = 0; nt < 7; nt++) {
      int j = (nt << 4) + r16;
#pragma unroll
      for (int reg = 0; reg < 4; reg++) {
        int i = ibase + reg;
        s[reg][nt] = (i < NTOK && j < NTOK) ? sc[sel][nt][reg] : -1.0e30f;
      }
    }
#pragma unroll
    for (int reg = 0; reg < 4; reg++) {
      float m = -3.0e38f;
#pragma unroll
      for (int nt = 0; nt < 7; nt++) m = fmaxf(m, s[reg][nt]);
#pragma unroll
      for (int d = 8; d; d >>= 1) m = fmaxf(m, __shfl_xor(m, d));
      float sum = 0.f;
#pragma unroll
      for (int nt = 0; nt < 7; nt++) { s[reg][nt] = __expf(s[reg][nt] - m); sum += s[reg][nt]; }
#pragma unroll
      for (int d = 8; d; d >>= 1) sum += __shfl_xor(sum, d);
      float inv = 1.f / sum;
#pragma unroll
      for (int nt = 0; nt < 7; nt++)
        Ps[(ibase + reg) * PSTR + (nt << 4) + r16] =
            (short)f2bfbits(s[reg][nt] * inv);
    }
    // PV (same-wave LDS RAW, no barrier)
    f32x4_t o0 = {0.f, 0.f, 0.f, 0.f}, o1 = {0.f, 0.f, 0.f, 0.f};
#pragma unroll
    for (int kt = 0; kt < 4; kt++) {
      bf16x8_t ap = *(const bf16x8_t*)&Ps[(mtile * 16 + r16) * PSTR + (kt << 5) + (q << 3)];
      bf16x8_t bv0 = *(const bf16x8_t*)&Vt[r16 * PSTR + (kt << 5) + (q << 3)];
      bf16x8_t bv1 = *(const bf16x8_t*)&Vt[(16 + r16) * PSTR + (kt << 5) + (q << 3)];
      o0 = __builtin_amdgcn_mfma_f32_16x16x32_bf16(ap, bv0, o0, 0, 0, 0);
      o1 = __builtin_amdgcn_mfma_f32_16x16x32_bf16(ap, bv1, o1, 0, 0, 0);
    }
#pragma unroll
    for (int reg = 0; reg < 4; reg++) {
      int i = mtile * 16 + (q << 2) + reg;
      if (i < NTOK) {
        size_t ob = (size_t)(nw * NTOK + i) * 128 + h * 32;
        out[ob + r16] = f2bf(o0[reg]);
        out[ob + 16 + r16] = f2bf(o1[reg]);
      }
    }
  }
}

// ---------------------------------------------------------------------------
extern "C" void kernel_launch(void* const* d_in, const int* in_sizes, int n_in,
                              void* d_out, int out_size, void* d_ws, size_t ws_size,
                              hipStream_t stream) {
  const float* x      = (const float*)d_in[0];
  const float* n1w    = (const float*)d_in[1];
  const float* n1b    = (const float*)d_in[2];
  const float* qkv_w  = (const float*)d_in[3];
  const float* qkv_b  = (const float*)d_in[4];
  const float* btab   = (const float*)d_in[5];
  const float* proj_w = (const float*)d_in[6];
  const float* proj_b = (const float*)d_in[7];
  const float* n2w    = (const float*)d_in[8];
  const float* n2b    = (const float*)d_in[9];
  const float* fc1_w  = (const float*)d_in[10];
  const float* fc1_b  = (const float*)d_in[11];
  const float* fc2_w  = (const float*)d_in[12];
  const float* fc2_b  = (const float*)d_in[13];
  const int*   relidx = (const int*)d_in[14];

  // Layout (A = 50176*128*2 B = 12,845,056):
  //   ws[0,384K): bf16 weights; ws[384K,+176K): BmatT; then bscaled (1.5KB)
  //   R = ws+1MB: qkv [R,R+3A)  (x2/xn2 eliminated: proj+MLP fused)
  //   d_out scratch: attn = d_out[0,A)
  const size_t Asz = (size_t)TOK * 128 * 2;
  (void)Asz;
  char* ws = (char*)d_ws;
  bf16* wbf   = (bf16*)ws;
  bf16* qkvw16  = wbf;               // 49152
  bf16* projw16 = wbf + 49152;       // 16384
  bf16* fc1w16  = wbf + 65536;       // 65536
  bf16* fc2w16  = wbf + 131072;      // 65536
  float* BmatT = (float*)(ws + 393216);            // 4*98*112 fp32 = 175,616 B
  float* bsc   = (float*)(ws + 393216 + 175616);   // 384 fp32
  char* R = ws + (1 << 20);
  bf16* attn  = (bf16*)d_out;
  bf16* qkv   = (bf16*)R;
  float* out  = (float*)d_out;

  // 0. weight conversion (q pre-scaled) + bias matrix + scaled qkv bias
  setup_k<<<806, 256, 0, stream>>>(qkv_w, proj_w, fc1_w, fc2_w, wbf,
                                   btab, relidx, qkv_b, BmatT, bsc);
  // 1+2. fused LN1 + window partition + QKV GEMM (x read once)
  qkvln_k<<<TOK / 64, 256, 0, stream>>>(x, n1w, n1b, qkvw16, bsc, qkv);
  // 3. MFMA windowed attention
  attn_mfma_k<<<dim3(NWIN, NHEAD), 256, 0, stream>>>(qkv, BmatT, attn);
  // 4+5. fused proj + residual + LN2 + MLP + final residual (512 thr)
  projmlp_k<<<TOK / 128, 512, 0, stream>>>(
      attn, projw16, proj_b, x, n2w, n2b,
      fc1w16, fc2w16, fc1_b, fc2_b, out);
}

// Round 10
// 203.534 us; speedup vs baseline: 1.0303x; 1.0303x over previous
//
#include <hip/hip_runtime.h>
#include <hip/hip_bf16.h>

typedef __hip_bfloat16 bf16;
typedef unsigned short u16t;
typedef unsigned int u32t;
typedef __attribute__((ext_vector_type(8))) short bf16x8_t;
typedef __attribute__((ext_vector_type(4))) float f32x4_t;

#define DEVI static __device__ __forceinline__

DEVI float u2f(u32t bits) { union { u32t u; float f; } v; v.u = bits; return v.f; }
DEVI float bflo(u32t u) { return u2f((u & 0xffffu) << 16); }
DEVI float bfhi(u32t u) { return u2f(u & 0xffff0000u); }
DEVI float sh2f(short s) { return u2f(((u32t)(u16t)s) << 16); }
DEVI float bf2f(bf16 h) { return __bfloat162float(h); }
DEVI bf16 f2bf(float f) { return __float2bfloat16(f); }
DEVI u16t f2bfbits(float f) {
  bf16 h = __float2bfloat16(f);
  union { bf16 h; u16t u; } v; v.h = h; return v.u;
}

// async global->LDS, 16B per lane. LDS dest must be wave-uniform base + lane*16.
DEVI void gl_lds16(const void* g, void* l) {
  __builtin_amdgcn_global_load_lds(
      (const __attribute__((address_space(1))) unsigned int*)g,
      (__attribute__((address_space(3))) unsigned int*)l, 16, 0, 0);
}

// Problem constants: x (2,8,56,56,128); windows (2,7,7) -> N=98; NW=512
#define TOK   50176
#define NWIN  512
#define NTOK  98
#define NHEAD 4
#define HDIM  32
#define QSCALE 0.17677669529663687f

// ---------------------------------------------------------------------------
// Merged setup kernel: blocks [0,768) convert weights fp32->bf16 (q-rows
// pre-scaled); blocks [768,806) build BmatT + scaled qkv bias.
// ---------------------------------------------------------------------------
__global__ __launch_bounds__(256) void setup_k(
    const float* __restrict__ a, const float* __restrict__ b,
    const float* __restrict__ c, const float* __restrict__ d,
    bf16* __restrict__ o,
    const float* __restrict__ btab, const int* __restrict__ relidx,
    const float* __restrict__ qkv_b, float* __restrict__ BmatT,
    float* __restrict__ bsc) {
  int bx = blockIdx.x;
  if (bx < 768) {
    int i = bx * 256 + threadIdx.x;
    const float* s; int off;
    if (i < 49152)       { s = a; off = 0; }
    else if (i < 65536)  { s = b; off = 49152; }
    else if (i < 131072) { s = c; off = 65536; }
    else                 { s = d; off = 131072; }
    float v = s[i - off];
    if (i < 16384) v *= QSCALE;     // q-slice of qkv_w
    o[i] = f2bf(v);
  } else {
    int idx = (bx - 768) * 256 + threadIdx.x;
    if (idx < NTOK * NTOK) {
      int i = idx / NTOK, j = idx - i * NTOK;
      int r = relidx[idx] * NHEAD;
#pragma unroll
      for (int h = 0; h < NHEAD; h++)
        BmatT[(size_t)(h * NTOK + j) * 112 + i] = btab[r + h];
    }
    if (bx == 768 && threadIdx.x < 384)
      bsc[threadIdx.x] = qkv_b[threadIdx.x] * (threadIdx.x < 128 ? QSCALE : 1.0f);
  }
}

// window-reverse: grow = nw*98+n -> token index
DEVI int winrev(int grow) {
  int nw = grow / NTOK, n = grow - nw * NTOK;
  int wq = nw & 7, hq = (nw >> 3) & 7, dq = (nw >> 6) & 3, bb = nw >> 8;
  int wr = n % 7; int q7 = n / 7; int hr = q7 % 7, dr = q7 / 7;
  return ((bb * 8 + dq * 2 + dr) * 56 + hq * 7 + hr) * 56 + wq * 7 + wr;
}

// ---------------------------------------------------------------------------
// Fused LN1 + window partition + QKV GEMM — 512 threads, 128-row tiles.
// Round-9 analysis: the 256-thr/64-row version ran 784 blocks against 768
// resident slots (3/CU) -> a 16-block straggler round ~doubles elapsed time
// in the latency-bound regime; and 3 waves/SIMD is below the proven-good 4.
// Now: 392 blocks <= 512 slots (2/CU x 8 waves = 4 waves/SIMD), single
// dispatch round. Per-wave: one 16-row m-tile, acc[8], 3 col-chunks of 128.
// LN1 arithmetic and MFMA K-chain per output element unchanged -> bit-
// identical output. LDS 64KB.
// ---------------------------------------------------------------------------
__global__ __launch_bounds__(512, 4) void qkvln_k(
    const float* __restrict__ x, const float* __restrict__ n1w,
    const float* __restrict__ n1b, const bf16* __restrict__ W,
    const float* __restrict__ bsc, bf16* __restrict__ qkvO)
{
  __shared__ __align__(16) short As[128 * 128];   // 32KB LN1'd A tile (swz)
  __shared__ __align__(16) short Bs[128 * 128];   // 32KB weights / C staging
  const int tid = threadIdx.x;
  const int rowBase = blockIdx.x << 7;
  const int wv = tid >> 6, lane = tid & 63;
  const int q = lane >> 4, r16 = lane & 15;

  // stage weight chunk 0 (async DMA overlaps LN compute below)
#pragma unroll
  for (int t = 0; t < 4; t++) {
    int f = tid + (t << 9);
    int row = f >> 4, cs = (f & 15) ^ (row & 15);
    gl_lds16((const u16t*)W + (size_t)row * 128 + (cs << 3), &Bs[f << 3]);
  }

  // LN1 + window partition into As (bit-identical arithmetic to ln1_k)
  {
    const int c = lane << 1;
    float lw0 = n1w[c], lw1 = n1w[c + 1];
    float lb0 = n1b[c], lb1 = n1b[c + 1];
#pragma unroll
    for (int rr = 0; rr < 16; rr++) {
      int row = (wv << 4) + rr;
      int tt = winrev(rowBase + row);
      float2 xv = *(const float2*)(x + (size_t)tt * 128 + c);
      float x0 = xv.x, x1 = xv.y;
      float s = x0 + x1, ss = x0 * x0 + x1 * x1;
#pragma unroll
      for (int m = 32; m; m >>= 1) { s += __shfl_xor(s, m); ss += __shfl_xor(ss, m); }
      float mean = s * 0.0078125f;
      float var = ss * 0.0078125f - mean * mean;
      float rstd = rsqrtf(var + 1e-5f);
      float y0 = (x0 - mean) * rstd * lw0 + lb0;
      float y1 = (x1 - mean) * rstd * lw1 + lb1;
      u32t ov = ((u32t)f2bfbits(y1) << 16) | (u32t)f2bfbits(y0);
      int slot = (lane >> 2) ^ (row & 15);
      *(u32t*)&As[(row << 7) + (slot << 3) + ((lane & 3) << 1)] = ov;
    }
  }
  __syncthreads();

#pragma unroll 1
  for (int qt = 0; qt < 3; qt++) {
    if (qt > 0) {
#pragma unroll
      for (int t = 0; t < 4; t++) {
        int f = tid + (t << 9);
        int row = f >> 4, cs = (f & 15) ^ (row & 15);
        gl_lds16((const u16t*)W + (size_t)((qt << 7) + row) * 128 + (cs << 3),
                 &Bs[f << 3]);
      }
      __syncthreads();
    }
    f32x4_t acc[8];
#pragma unroll
    for (int j = 0; j < 8; j++) acc[j] = (f32x4_t){0.f, 0.f, 0.f, 0.f};
#pragma unroll
    for (int ks = 0; ks < 4; ks++) {
      int rowA = (wv << 4) + r16;
      int slotA = ((ks << 2) + q) ^ (rowA & 15);
      bf16x8_t af = *(const bf16x8_t*)&As[(rowA << 7) + (slotA << 3)];
      bf16x8_t bfr[8];
#pragma unroll
      for (int nt = 0; nt < 8; nt++) {
        int row = (nt << 4) + r16;
        int slot = ((ks << 2) + q) ^ (row & 15);
        bfr[nt] = *(const bf16x8_t*)&Bs[(row << 7) + (slot << 3)];
      }
#pragma unroll
      for (int nt = 0; nt < 8; nt++)
        acc[nt] = __builtin_amdgcn_mfma_f32_16x16x32_bf16(af, bfr[nt], acc[nt], 0, 0, 0);
    }
    float bv[8];
#pragma unroll
    for (int nt = 0; nt < 8; nt++) bv[nt] = bsc[(qt << 7) + (nt << 4) + r16];
    __syncthreads();   // MFMA Bs reads done before overwrite
    // C + bias -> Bs bf16 (128 rows x 128 cols)
#pragma unroll
    for (int reg = 0; reg < 4; reg++) {
      int lrow = (wv << 4) + (q << 2) + reg;
#pragma unroll
      for (int nt = 0; nt < 8; nt++)
        Bs[(lrow << 7) + (nt << 4) + r16] = (short)f2bfbits(acc[nt][reg] + bv[nt]);
    }
    __syncthreads();
    // coalesced uint4 out
#pragma unroll
    for (int t = 0; t < 4; t++) {
      int f = tid + (t << 9);
      int row = f >> 4, c8 = (f & 15) << 3;
      size_t ob = (size_t)(rowBase + row) * 384 + (qt << 7) + c8;
      *(uint4*)((u16t*)qkvO + ob) = *(const uint4*)&Bs[(row << 7) + c8];
    }
    if (qt < 2) __syncthreads();   // out reads done before next chunk staging
  }
}

// ---------------------------------------------------------------------------
// proj + window reverse + residual + fused LN2 -> x2, xn2 (round-7 verified).
// 512 threads, 8 waves x one 16-row m-tile; LDS 64KB -> 2 blocks/CU.
// ---------------------------------------------------------------------------
__global__ __launch_bounds__(512, 4) void proj_k(
    const bf16* __restrict__ A, const bf16* __restrict__ W,
    const float* __restrict__ bias, const float* __restrict__ resX,
    bf16* __restrict__ outB, bf16* __restrict__ outB2,
    const float* __restrict__ lnw, const float* __restrict__ lnb)
{
  __shared__ __align__(16) short As[128 * 128];   // 32KB A tile / C staging
  __shared__ __align__(16) short Bs[128 * 128];   // 32KB proj weights
  const int tid = threadIdx.x;
  const int rowBase = blockIdx.x << 7;
  const int wv = tid >> 6, lane = tid & 63;
  const int q = lane >> 4, r16 = lane & 15;
  const int mB = wv << 4;                         // one 16-row m-tile per wave

  // stage A (128x128) + W (128x128), 4+4 chunks/thread
#pragma unroll
  for (int t = 0; t < 4; t++) {
    int f = tid + (t << 9);
    int row = f >> 4, cs = (f & 15) ^ (row & 15);
    gl_lds16((const u16t*)A + (size_t)(rowBase + row) * 128 + (cs << 3),
             &As[f << 3]);
  }
#pragma unroll
  for (int t = 0; t < 4; t++) {
    int f = tid + (t << 9);
    int row = f >> 4, cs = (f & 15) ^ (row & 15);
    gl_lds16((const u16t*)W + (size_t)row * 128 + (cs << 3), &Bs[f << 3]);
  }
  __syncthreads();

  f32x4_t acc[8];
#pragma unroll
  for (int j = 0; j < 8; j++) acc[j] = (f32x4_t){0.f, 0.f, 0.f, 0.f};
#pragma unroll
  for (int ks = 0; ks < 4; ks++) {
    int rowA = mB + r16;
    int slotA = ((ks << 2) + q) ^ (rowA & 15);
    bf16x8_t af = *(const bf16x8_t*)&As[(rowA << 7) + (slotA << 3)];
    bf16x8_t bfr[8];
#pragma unroll
    for (int nt = 0; nt < 8; nt++) {
      int row = (nt << 4) + r16;
      int slot = ((ks << 2) + q) ^ (row & 15);
      bfr[nt] = *(const bf16x8_t*)&Bs[(row << 7) + (slot << 3)];
    }
#pragma unroll
    for (int nt = 0; nt < 8; nt++)
      acc[nt] = __builtin_amdgcn_mfma_f32_16x16x32_bf16(af, bfr[nt], acc[nt], 0, 0, 0);
  }
  __syncthreads();

  float bv[8];
#pragma unroll
  for (int nt = 0; nt < 8; nt++) bv[nt] = bias[(nt << 4) + r16];

  // C + bias -> As bf16 (stride 128), each wave its own 16 rows
#pragma unroll
  for (int reg = 0; reg < 4; reg++) {
    int lrow = mB + (q << 2) + reg;
#pragma unroll
    for (int nt = 0; nt < 8; nt++)
      As[(lrow << 7) + (nt << 4) + r16] = (short)f2bfbits(acc[nt][reg] + bv[nt]);
  }
  __syncthreads();
  // residual add (token-addressed), write x2, update LDS with x2
#pragma unroll
  for (int t = 0; t < 4; t++) {
    int f = tid + (t << 9);
    int row = f >> 4, c8 = (f & 15) << 3;
    int tt = winrev(rowBase + row);
    size_t ob = (size_t)tt * 128 + c8;
    float4 r0 = *(const float4*)(resX + ob);
    float4 r1 = *(const float4*)(resX + ob + 4);
    short* cs = &As[(row << 7) + c8];
    u16t pk[8];
    pk[0] = f2bfbits(sh2f(cs[0]) + r0.x); pk[1] = f2bfbits(sh2f(cs[1]) + r0.y);
    pk[2] = f2bfbits(sh2f(cs[2]) + r0.z); pk[3] = f2bfbits(sh2f(cs[3]) + r0.w);
    pk[4] = f2bfbits(sh2f(cs[4]) + r1.x); pk[5] = f2bfbits(sh2f(cs[5]) + r1.y);
    pk[6] = f2bfbits(sh2f(cs[6]) + r1.z); pk[7] = f2bfbits(sh2f(cs[7]) + r1.w);
    *(uint4*)((u16t*)outB + ob) = *(const uint4*)pk;
    *(uint4*)cs = *(const uint4*)pk;
  }
  __syncthreads();
  // fused LN2: one wave per row, 16 rows/wave, coalesced u32 LDS reads
  const int c = lane << 1;
  float2 lw = *(const float2*)(lnw + c);
  float2 lb = *(const float2*)(lnb + c);
#pragma unroll 4
  for (int rr = 0; rr < 16; rr++) {
    int row = (wv << 4) + rr;
    u32t u = *(const u32t*)&As[(row << 7) + c];
    float x0 = bflo(u), x1 = bfhi(u);
    float s = x0 + x1, ss = x0 * x0 + x1 * x1;
#pragma unroll
    for (int m = 32; m; m >>= 1) { s += __shfl_xor(s, m); ss += __shfl_xor(ss, m); }
    float mean = s * 0.0078125f;
    float var = ss * 0.0078125f - mean * mean;
    float rstd = rsqrtf(var + 1e-5f);
    float y0 = (x0 - mean) * rstd * lw.x + lb.x;
    float y1 = (x1 - mean) * rstd * lw.y + lb.y;
    int tt = winrev(rowBase + row);
    u32t ov = ((u32t)f2bfbits(y1) << 16) | (u32t)f2bfbits(y0);
    *(u32t*)((u16t*)outB2 + (size_t)tt * 128 + c) = ov;
  }
}

// ---------------------------------------------------------------------------
// Fused MLP: out = x2 + (GELU(xn2 @ fc1_w^T + b1) @ fc2_w^T + b2), fp32 out.
// 512 threads (8 waves, one 16-row m-tile each). LDS 80KB -> 2 blocks/CU.
// (round-7 verified; round-9 showed fusing proj into this spills ~45MB.)
// ---------------------------------------------------------------------------
__global__ __launch_bounds__(512, 4) void mlp_fused_k(
    const bf16* __restrict__ Axn, const bf16* __restrict__ F1,
    const bf16* __restrict__ F2, const float* __restrict__ b1,
    const float* __restrict__ b2, const bf16* __restrict__ resB,
    float* __restrict__ out)
{
  __shared__ __align__(16) char smem[81920];
  short* As  = (short*)smem;             // [128][128] xn2 tile, 32KB
  short* F1s = (short*)(smem + 32768);   // [64][128] fc1 chunk, 16KB
  short* F2s = (short*)(smem + 49152);   // [128][64] fc2 chunk, 16KB
  short* Hs  = (short*)(smem + 65536);   // [128][64] H chunk,   16KB
  float* Cf  = (float*)smem;             // [128][132] fp32 epilogue (67.5KB)

  const int tid = threadIdx.x;
  const int rowBase = blockIdx.x << 7;
  const int wv = tid >> 6, lane = tid & 63;
  const int q = lane >> 4, r16 = lane & 15;
  const int mB = wv << 4;                // one 16-row m-tile per wave

#pragma unroll
  for (int t = 0; t < 4; t++) {
    int f = tid + (t << 9);
    int row = f >> 4, cs = (f & 15) ^ (row & 15);
    gl_lds16((const u16t*)Axn + (size_t)(rowBase + row) * 128 + (cs << 3),
             &As[f << 3]);
  }
#pragma unroll
  for (int t = 0; t < 2; t++) {
    int f = tid + (t << 9);
    int row = f >> 4, cs = (f & 15) ^ (row & 15);
    gl_lds16((const u16t*)F1 + (size_t)row * 128 + (cs << 3), &F1s[f << 3]);
  }
#pragma unroll
  for (int t = 0; t < 2; t++) {
    int f = tid + (t << 9);
    int row = f >> 3, cs = (f & 7) ^ (row & 7);
    gl_lds16((const u16t*)F2 + (size_t)row * 512 + (cs << 3), &F2s[f << 3]);
  }
  __syncthreads();

  f32x4_t oacc[8];
#pragma unroll
  for (int j = 0; j < 8; j++) oacc[j] = (f32x4_t){0.f, 0.f, 0.f, 0.f};

#pragma unroll 1
  for (int c = 0; c < 8; c++) {
    if (c > 0) {
#pragma unroll
      for (int t = 0; t < 2; t++) {
        int f = tid + (t << 9);
        int row = f >> 4, cs = (f & 15) ^ (row & 15);
        gl_lds16((const u16t*)F1 + (size_t)(c * 64 + row) * 128 + (cs << 3),
                 &F1s[f << 3]);
      }
#pragma unroll
      for (int t = 0; t < 2; t++) {
        int f = tid + (t << 9);
        int row = f >> 3, cs = (f & 7) ^ (row & 7);
        gl_lds16((const u16t*)F2 + (size_t)row * 512 + c * 64 + (cs << 3),
                 &F2s[f << 3]);
      }
      __syncthreads();
    }

    // fc1: H-chunk rows mB..mB+15 (K=128, 4 ks; 16 MFMA/wave)
    f32x4_t hacc[4];
#pragma unroll
    for (int j = 0; j < 4; j++) hacc[j] = (f32x4_t){0.f, 0.f, 0.f, 0.f};
#pragma unroll
    for (int ks = 0; ks < 4; ks++) {
      int rowA = mB + r16;
      int slotA = ((ks << 2) + q) ^ (rowA & 15);
      bf16x8_t af = *(const bf16x8_t*)&As[(rowA << 7) + (slotA << 3)];
      bf16x8_t bfr[4];
#pragma unroll
      for (int nt = 0; nt < 4; nt++) {
        int row = (nt << 4) + r16;
        int slot = ((ks << 2) + q) ^ (row & 15);
        bfr[nt] = *(const bf16x8_t*)&F1s[(row << 7) + (slot << 3)];
      }
#pragma unroll
      for (int nt = 0; nt < 4; nt++)
        hacc[nt] = __builtin_amdgcn_mfma_f32_16x16x32_bf16(af, bfr[nt], hacc[nt], 0, 0, 0);
    }

    // bias + GELU -> Hs bf16 (8-short-slot XOR swizzle on row&7)
    float bb[4];
#pragma unroll
    for (int nt = 0; nt < 4; nt++) bb[nt] = b1[c * 64 + (nt << 4) + r16];
#pragma unroll
    for (int reg = 0; reg < 4; reg++) {
      int lrow = mB + (q << 2) + reg;
#pragma unroll
      for (int nt = 0; nt < 4; nt++) {
        float v = hacc[nt][reg] + bb[nt];
        v = 0.5f * v * (1.0f + erff(v * 0.70710678118654752f));
        int col = (nt << 4) + r16;
        int sp = (col >> 3) ^ (lrow & 7);
        Hs[(lrow << 6) + (sp << 3) + (col & 7)] = (short)f2bfbits(v);
      }
    }
    __syncthreads();

    // fc2: out += Hc @ F2c^T  (K=64, 2 ks; 16 MFMA/wave)
#pragma unroll
    for (int ks = 0; ks < 2; ks++) {
      int rowA = mB + r16;
      int slotA = ((ks << 2) + q) ^ (rowA & 7);
      bf16x8_t af = *(const bf16x8_t*)&Hs[(rowA << 6) + (slotA << 3)];
      bf16x8_t bfr[8];
#pragma unroll
      for (int nt = 0; nt < 8; nt++) {
        int row = (nt << 4) + r16;
        int slot = ((ks << 2) + q) ^ (row & 7);
        bfr[nt] = *(const bf16x8_t*)&F2s[(row << 6) + (slot << 3)];
      }
#pragma unroll
      for (int nt = 0; nt < 8; nt++)
        oacc[nt] = __builtin_amdgcn_mfma_f32_16x16x32_bf16(af, bfr[nt], oacc[nt], 0, 0, 0);
    }
    __syncthreads();   // guards next chunk's weight staging / Hs reuse
  }

  // epilogue: Cf = oacc + b2 (stride 132), coalesced float4 out + residual
  float bv[8];
#pragma unroll
  for (int nt = 0; nt < 8; nt++) bv[nt] = b2[(nt << 4) + r16];
#pragma unroll
  for (int reg = 0; reg < 4; reg++) {
    int lrow = mB + (q << 2) + reg;
#pragma unroll
    for (int nt = 0; nt < 8; nt++)
      Cf[lrow * 132 + (nt << 4) + r16] = oacc[nt][reg] + bv[nt];
  }
  __syncthreads();
#pragma unroll
  for (int t = 0; t < 8; t++) {
    int f = tid + (t << 9);
    int row = f >> 5, c4 = (f & 31) << 2;
    size_t ob = (size_t)(rowBase + row) * 128 + c4;
    const u16t* rp = (const u16t*)resB + ob;
    const float* cp = &Cf[row * 132 + c4];
    float4 v;
    v.x = cp[0] + sh2f(rp[0]);
    v.y = cp[1] + sh2f(rp[1]);
    v.z = cp[2] + sh2f(rp[2]);
    v.w = cp[3] + sh2f(rp[3]);
    *(float4*)(out + ob) = v;
  }
}

// ---------------------------------------------------------------------------
// MFMA windowed attention (verified round-1 structure; bias pre-loaded into
// the QK accumulator in C-layout; q pre-scaled at weight conversion).
// ---------------------------------------------------------------------------
#define PSTR 136
__global__ __launch_bounds__(256) void attn_mfma_k(
    const bf16* __restrict__ qkv, const float* __restrict__ BmatT,
    bf16* __restrict__ out)
{
  __shared__ short Vt[32 * PSTR];    // V^T [d][j], zero-padded j>=98
  __shared__ short Ps[112 * PSTR];   // P [i][j] bf16, cols 112..135 zeroed
  const int nw = blockIdx.x, h = blockIdx.y;
  const int tid = threadIdx.x;
  const int wv = tid >> 6, lane = tid & 63;
  const int q = lane >> 4, r16 = lane & 15;

  for (int idx = tid; idx < 32 * 38; idx += 256) {
    int d = idx / 38, j = 98 + idx % 38;
    Vt[d * PSTR + j] = 0;
  }
  for (int idx = tid; idx < 112 * 12; idx += 256) {
    int r = idx / 12, c = (idx % 12) << 1;
    *(u32t*)&Ps[r * PSTR + 112 + c] = 0;
  }
  for (int idx = tid; idx < NTOK * 16; idx += 256) {
    int j = idx >> 4, d2 = (idx & 15) << 1;
    u32t uv = *(const u32t*)((const u16t*)qkv +
                             (size_t)(nw * NTOK + j) * 384 + 256 + h * 32 + d2);
    Vt[d2 * PSTR + j] = (short)(uv & 0xffffu);
    Vt[(d2 + 1) * PSTR + j] = (short)(uv >> 16);
  }
  __syncthreads();

  const int mt0 = wv;
  const bool has2 = (wv + 4) < 7;
  const int mt1 = has2 ? wv + 4 : wv;

  int i0 = mt0 * 16 + r16; if (i0 > NTOK - 1) i0 = NTOK - 1;
  int i1 = mt1 * 16 + r16; if (i1 > NTOK - 1) i1 = NTOK - 1;
  bf16x8_t aq0 = *(const bf16x8_t*)((const u16t*)qkv +
      (size_t)(nw * NTOK + i0) * 384 + h * 32 + (q << 3));
  bf16x8_t aq1 = *(const bf16x8_t*)((const u16t*)qkv +
      (size_t)(nw * NTOK + i1) * 384 + h * 32 + (q << 3));

  f32x4_t sc[2][7];
#pragma unroll
  for (int nt = 0; nt < 7; nt++) {
    int j = (nt << 4) + r16; if (j > NTOK - 1) j = NTOK - 1;
    const float* bRow = &BmatT[(size_t)(h * NTOK + j) * 112];
    bf16x8_t bk = *(const bf16x8_t*)((const u16t*)qkv +
        (size_t)(nw * NTOK + j) * 384 + 128 + h * 32 + (q << 3));
    f32x4_t b0 = *(const f32x4_t*)&bRow[mt0 * 16 + (q << 2)];
    f32x4_t b1 = *(const f32x4_t*)&bRow[mt1 * 16 + (q << 2)];
    sc[0][nt] = __builtin_amdgcn_mfma_f32_16x16x32_bf16(aq0, bk, b0, 0, 0, 0);
    sc[1][nt] = __builtin_amdgcn_mfma_f32_16x16x32_bf16(aq1, bk, b1, 0, 0, 0);
  }

#pragma unroll
  for (int sel = 0; sel < 2; sel++) {
    if (sel == 1 && !has2) break;
    int mtile = sel ? mt1 : mt0;
    int ibase = mtile * 16 + (q << 2);
    float s[4][7];
#pragma unroll
    for (int nt = 0; nt < 7; nt++) {
      int j = (nt << 4) + r16;
#pragma unroll
      for (int reg = 0; reg < 4; reg++) {
        int i = ibase + reg;
        s[reg][nt] = (i < NTOK && j < NTOK) ? sc[sel][nt][reg] : -1.0e30f;
      }
    }
#pragma unroll
    for (int reg = 0; reg < 4; reg++) {
      float m = -3.0e38f;
#pragma unroll
      for (int nt = 0; nt < 7; nt++) m = fmaxf(m, s[reg][nt]);
#pragma unroll
      for (int d = 8; d; d >>= 1) m = fmaxf(m, __shfl_xor(m, d));
      float sum = 0.f;
#pragma unroll
      for (int nt = 0; nt < 7; nt++) { s[reg][nt] = __expf(s[reg][nt] - m); sum += s[reg][nt]; }
#pragma unroll
      for (int d = 8; d; d >>= 1) sum += __shfl_xor(sum, d);
      float inv = 1.f / sum;
#pragma unroll
      for (int nt = 0; nt < 7; nt++)
        Ps[(ibase + reg) * PSTR + (nt << 4) + r16] =
            (short)f2bfbits(s[reg][nt] * inv);
    }
    // PV (same-wave LDS RAW, no barrier)
    f32x4_t o0 = {0.f, 0.f, 0.f, 0.f}, o1 = {0.f, 0.f, 0.f, 0.f};
#pragma unroll
    for (int kt = 0; kt < 4; kt++) {
      bf16x8_t ap = *(const bf16x8_t*)&Ps[(mtile * 16 + r16) * PSTR + (kt << 5) + (q << 3)];
      bf16x8_t bv0 = *(const bf16x8_t*)&Vt[r16 * PSTR + (kt << 5) + (q << 3)];
      bf16x8_t bv1 = *(const bf16x8_t*)&Vt[(16 + r16) * PSTR + (kt << 5) + (q << 3)];
      o0 = __builtin_amdgcn_mfma_f32_16x16x32_bf16(ap, bv0, o0, 0, 0, 0);
      o1 = __builtin_amdgcn_mfma_f32_16x16x32_bf16(ap, bv1, o1, 0, 0, 0);
    }
#pragma unroll
    for (int reg = 0; reg < 4; reg++) {
      int i = mtile * 16 + (q << 2) + reg;
      if (i < NTOK) {
        size_t ob = (size_t)(nw * NTOK + i) * 128 + h * 32;
        out[ob + r16] = f2bf(o0[reg]);
        out[ob + 16 + r16] = f2bf(o1[reg]);
      }
    }
  }
}

// ---------------------------------------------------------------------------
extern "C" void kernel_launch(void* const* d_in, const int* in_sizes, int n_in,
                              void* d_out, int out_size, void* d_ws, size_t ws_size,
                              hipStream_t stream) {
  const float* x      = (const float*)d_in[0];
  const float* n1w    = (const float*)d_in[1];
  const float* n1b    = (const float*)d_in[2];
  const float* qkv_w  = (const float*)d_in[3];
  const float* qkv_b  = (const float*)d_in[4];
  const float* btab   = (const float*)d_in[5];
  const float* proj_w = (const float*)d_in[6];
  const float* proj_b = (const float*)d_in[7];
  const float* n2w    = (const float*)d_in[8];
  const float* n2b    = (const float*)d_in[9];
  const float* fc1_w  = (const float*)d_in[10];
  const float* fc1_b  = (const float*)d_in[11];
  const float* fc2_w  = (const float*)d_in[12];
  const float* fc2_b  = (const float*)d_in[13];
  const int*   relidx = (const int*)d_in[14];

  // Layout (A = 50176*128*2 B = 12,845,056):
  //   ws[0,384K): bf16 weights; ws[384K,+176K): BmatT; then bscaled (1.5KB)
  //   R = ws+1MB: qkv [R,R+3A) -> x2 [R,R+A), xn2 [R+A,R+2A)
  //   d_out scratch: attn = d_out[0,A)
  const size_t Asz = (size_t)TOK * 128 * 2;
  char* ws = (char*)d_ws;
  bf16* wbf   = (bf16*)ws;
  bf16* qkvw16  = wbf;               // 49152
  bf16* projw16 = wbf + 49152;       // 16384
  bf16* fc1w16  = wbf + 65536;       // 65536
  bf16* fc2w16  = wbf + 131072;      // 65536
  float* BmatT = (float*)(ws + 393216);            // 4*98*112 fp32 = 175,616 B
  float* bsc   = (float*)(ws + 393216 + 175616);   // 384 fp32
  char* R = ws + (1 << 20);
  bf16* attn  = (bf16*)d_out;
  bf16* qkv   = (bf16*)R;
  bf16* x2    = (bf16*)R;
  bf16* xn2   = (bf16*)(R + Asz);
  float* out  = (float*)d_out;

  // 0. weight conversion (q pre-scaled) + bias matrix + scaled qkv bias
  setup_k<<<806, 256, 0, stream>>>(qkv_w, proj_w, fc1_w, fc2_w, wbf,
                                   btab, relidx, qkv_b, BmatT, bsc);
  // 1+2. fused LN1 + window partition + QKV GEMM (512 thr, 392 blocks)
  qkvln_k<<<TOK / 128, 512, 0, stream>>>(x, n1w, n1b, qkvw16, bsc, qkv);
  // 3. MFMA windowed attention
  attn_mfma_k<<<dim3(NWIN, NHEAD), 256, 0, stream>>>(qkv, BmatT, attn);
  // 4. proj + window reverse + residual + fused LN2 -> x2, xn2 (512 thr)
  proj_k<<<TOK / 128, 512, 0, stream>>>(
      attn, projw16, proj_b, x, x2, xn2, n2w, n2b);
  // 5. fused MLP: fc1 + GELU + fc2 + residual, hmid stays in LDS (512 thr)
  mlp_fused_k<<<TOK / 128, 512, 0, stream>>>(
      xn2, fc1w16, fc2w16, fc1_b, fc2_b, x2, out);
}

// Round 11
// 201.577 us; speedup vs baseline: 1.0403x; 1.0097x over previous
//
#include <hip/hip_runtime.h>
#include <hip/hip_bf16.h>

typedef __hip_bfloat16 bf16;
typedef unsigned short u16t;
typedef unsigned int u32t;
typedef __attribute__((ext_vector_type(8))) short bf16x8_t;
typedef __attribute__((ext_vector_type(4))) float f32x4_t;

#define DEVI static __device__ __forceinline__

DEVI float u2f(u32t bits) { union { u32t u; float f; } v; v.u = bits; return v.f; }
DEVI float bflo(u32t u) { return u2f((u & 0xffffu) << 16); }
DEVI float bfhi(u32t u) { return u2f(u & 0xffff0000u); }
DEVI float sh2f(short s) { return u2f(((u32t)(u16t)s) << 16); }
DEVI float bf2f(bf16 h) { return __bfloat162float(h); }
DEVI bf16 f2bf(float f) { return __float2bfloat16(f); }
DEVI u16t f2bfbits(float f) {
  bf16 h = __float2bfloat16(f);
  union { bf16 h; u16t u; } v; v.h = h; return v.u;
}

// async global->LDS, 16B per lane. LDS dest must be wave-uniform base + lane*16.
DEVI void gl_lds16(const void* g, void* l) {
  __builtin_amdgcn_global_load_lds(
      (const __attribute__((address_space(1))) unsigned int*)g,
      (__attribute__((address_space(3))) unsigned int*)l, 16, 0, 0);
}

// Problem constants: x (2,8,56,56,128); windows (2,7,7) -> N=98; NW=512
#define TOK   50176
#define NWIN  512
#define NTOK  98
#define NHEAD 4
#define HDIM  32
#define QSCALE 0.17677669529663687f

// ---------------------------------------------------------------------------
// Merged setup kernel: blocks [0,768) convert weights fp32->bf16 (q-rows
// pre-scaled); blocks [768,806) build BmatT + scaled qkv bias.
// ---------------------------------------------------------------------------
__global__ __launch_bounds__(256) void setup_k(
    const float* __restrict__ a, const float* __restrict__ b,
    const float* __restrict__ c, const float* __restrict__ d,
    bf16* __restrict__ o,
    const float* __restrict__ btab, const int* __restrict__ relidx,
    const float* __restrict__ qkv_b, float* __restrict__ BmatT,
    float* __restrict__ bsc) {
  int bx = blockIdx.x;
  if (bx < 768) {
    int i = bx * 256 + threadIdx.x;
    const float* s; int off;
    if (i < 49152)       { s = a; off = 0; }
    else if (i < 65536)  { s = b; off = 49152; }
    else if (i < 131072) { s = c; off = 65536; }
    else                 { s = d; off = 131072; }
    float v = s[i - off];
    if (i < 16384) v *= QSCALE;     // q-slice of qkv_w
    o[i] = f2bf(v);
  } else {
    int idx = (bx - 768) * 256 + threadIdx.x;
    if (idx < NTOK * NTOK) {
      int i = idx / NTOK, j = idx - i * NTOK;
      int r = relidx[idx] * NHEAD;
#pragma unroll
      for (int h = 0; h < NHEAD; h++)
        BmatT[(size_t)(h * NTOK + j) * 112 + i] = btab[r + h];
    }
    if (bx == 768 && threadIdx.x < 384)
      bsc[threadIdx.x] = qkv_b[threadIdx.x] * (threadIdx.x < 128 ? QSCALE : 1.0f);
  }
}

// window-reverse: grow = nw*98+n -> token index
DEVI int winrev(int grow) {
  int nw = grow / NTOK, n = grow - nw * NTOK;
  int wq = nw & 7, hq = (nw >> 3) & 7, dq = (nw >> 6) & 3, bb = nw >> 8;
  int wr = n % 7; int q7 = n / 7; int hr = q7 % 7, dr = q7 / 7;
  return ((bb * 8 + dq * 2 + dr) * 56 + hq * 7 + hr) * 56 + wq * 7 + wr;
}

// ---------------------------------------------------------------------------
// Fused LN1 + window partition + QKV GEMM — 512 threads, 128-row tiles,
// 392 blocks (single dispatch round, 4 waves/SIMD). LDS 64KB.
// ---------------------------------------------------------------------------
__global__ __launch_bounds__(512, 4) void qkvln_k(
    const float* __restrict__ x, const float* __restrict__ n1w,
    const float* __restrict__ n1b, const bf16* __restrict__ W,
    const float* __restrict__ bsc, bf16* __restrict__ qkvO)
{
  __shared__ __align__(16) short As[128 * 128];   // 32KB LN1'd A tile (swz)
  __shared__ __align__(16) short Bs[128 * 128];   // 32KB weights / C staging
  const int tid = threadIdx.x;
  const int rowBase = blockIdx.x << 7;
  const int wv = tid >> 6, lane = tid & 63;
  const int q = lane >> 4, r16 = lane & 15;

  // stage weight chunk 0 (async DMA overlaps LN compute below)
#pragma unroll
  for (int t = 0; t < 4; t++) {
    int f = tid + (t << 9);
    int row = f >> 4, cs = (f & 15) ^ (row & 15);
    gl_lds16((const u16t*)W + (size_t)row * 128 + (cs << 3), &Bs[f << 3]);
  }

  // LN1 + window partition into As (bit-identical arithmetic to ln1_k)
  {
    const int c = lane << 1;
    float lw0 = n1w[c], lw1 = n1w[c + 1];
    float lb0 = n1b[c], lb1 = n1b[c + 1];
#pragma unroll
    for (int rr = 0; rr < 16; rr++) {
      int row = (wv << 4) + rr;
      int tt = winrev(rowBase + row);
      float2 xv = *(const float2*)(x + (size_t)tt * 128 + c);
      float x0 = xv.x, x1 = xv.y;
      float s = x0 + x1, ss = x0 * x0 + x1 * x1;
#pragma unroll
      for (int m = 32; m; m >>= 1) { s += __shfl_xor(s, m); ss += __shfl_xor(ss, m); }
      float mean = s * 0.0078125f;
      float var = ss * 0.0078125f - mean * mean;
      float rstd = rsqrtf(var + 1e-5f);
      float y0 = (x0 - mean) * rstd * lw0 + lb0;
      float y1 = (x1 - mean) * rstd * lw1 + lb1;
      u32t ov = ((u32t)f2bfbits(y1) << 16) | (u32t)f2bfbits(y0);
      int slot = (lane >> 2) ^ (row & 15);
      *(u32t*)&As[(row << 7) + (slot << 3) + ((lane & 3) << 1)] = ov;
    }
  }
  __syncthreads();

#pragma unroll 1
  for (int qt = 0; qt < 3; qt++) {
    if (qt > 0) {
#pragma unroll
      for (int t = 0; t < 4; t++) {
        int f = tid + (t << 9);
        int row = f >> 4, cs = (f & 15) ^ (row & 15);
        gl_lds16((const u16t*)W + (size_t)((qt << 7) + row) * 128 + (cs << 3),
                 &Bs[f << 3]);
      }
      __syncthreads();
    }
    f32x4_t acc[8];
#pragma unroll
    for (int j = 0; j < 8; j++) acc[j] = (f32x4_t){0.f, 0.f, 0.f, 0.f};
#pragma unroll
    for (int ks = 0; ks < 4; ks++) {
      int rowA = (wv << 4) + r16;
      int slotA = ((ks << 2) + q) ^ (rowA & 15);
      bf16x8_t af = *(const bf16x8_t*)&As[(rowA << 7) + (slotA << 3)];
      bf16x8_t bfr[8];
#pragma unroll
      for (int nt = 0; nt < 8; nt++) {
        int row = (nt << 4) + r16;
        int slot = ((ks << 2) + q) ^ (row & 15);
        bfr[nt] = *(const bf16x8_t*)&Bs[(row << 7) + (slot << 3)];
      }
#pragma unroll
      for (int nt = 0; nt < 8; nt++)
        acc[nt] = __builtin_amdgcn_mfma_f32_16x16x32_bf16(af, bfr[nt], acc[nt], 0, 0, 0);
    }
    float bv[8];
#pragma unroll
    for (int nt = 0; nt < 8; nt++) bv[nt] = bsc[(qt << 7) + (nt << 4) + r16];
    __syncthreads();   // MFMA Bs reads done before overwrite
    // C + bias -> Bs bf16 (128 rows x 128 cols)
#pragma unroll
    for (int reg = 0; reg < 4; reg++) {
      int lrow = (wv << 4) + (q << 2) + reg;
#pragma unroll
      for (int nt = 0; nt < 8; nt++)
        Bs[(lrow << 7) + (nt << 4) + r16] = (short)f2bfbits(acc[nt][reg] + bv[nt]);
    }
    __syncthreads();
    // coalesced uint4 out
#pragma unroll
    for (int t = 0; t < 4; t++) {
      int f = tid + (t << 9);
      int row = f >> 4, c8 = (f & 15) << 3;
      size_t ob = (size_t)(rowBase + row) * 384 + (qt << 7) + c8;
      *(uint4*)((u16t*)qkvO + ob) = *(const uint4*)&Bs[(row << 7) + c8];
    }
    if (qt < 2) __syncthreads();   // out reads done before next chunk staging
  }
}

// ---------------------------------------------------------------------------
// proj + window reverse + residual + fused LN2 -> x2, xn2 (round-7 verified).
// 512 threads, 8 waves x one 16-row m-tile; LDS 64KB -> 2 blocks/CU.
// ---------------------------------------------------------------------------
__global__ __launch_bounds__(512, 4) void proj_k(
    const bf16* __restrict__ A, const bf16* __restrict__ W,
    const float* __restrict__ bias, const float* __restrict__ resX,
    bf16* __restrict__ outB, bf16* __restrict__ outB2,
    const float* __restrict__ lnw, const float* __restrict__ lnb)
{
  __shared__ __align__(16) short As[128 * 128];   // 32KB A tile / C staging
  __shared__ __align__(16) short Bs[128 * 128];   // 32KB proj weights
  const int tid = threadIdx.x;
  const int rowBase = blockIdx.x << 7;
  const int wv = tid >> 6, lane = tid & 63;
  const int q = lane >> 4, r16 = lane & 15;
  const int mB = wv << 4;                         // one 16-row m-tile per wave

  // stage A (128x128) + W (128x128), 4+4 chunks/thread
#pragma unroll
  for (int t = 0; t < 4; t++) {
    int f = tid + (t << 9);
    int row = f >> 4, cs = (f & 15) ^ (row & 15);
    gl_lds16((const u16t*)A + (size_t)(rowBase + row) * 128 + (cs << 3),
             &As[f << 3]);
  }
#pragma unroll
  for (int t = 0; t < 4; t++) {
    int f = tid + (t << 9);
    int row = f >> 4, cs = (f & 15) ^ (row & 15);
    gl_lds16((const u16t*)W + (size_t)row * 128 + (cs << 3), &Bs[f << 3]);
  }
  __syncthreads();

  f32x4_t acc[8];
#pragma unroll
  for (int j = 0; j < 8; j++) acc[j] = (f32x4_t){0.f, 0.f, 0.f, 0.f};
#pragma unroll
  for (int ks = 0; ks < 4; ks++) {
    int rowA = mB + r16;
    int slotA = ((ks << 2) + q) ^ (rowA & 15);
    bf16x8_t af = *(const bf16x8_t*)&As[(rowA << 7) + (slotA << 3)];
    bf16x8_t bfr[8];
#pragma unroll
    for (int nt = 0; nt < 8; nt++) {
      int row = (nt << 4) + r16;
      int slot = ((ks << 2) + q) ^ (row & 15);
      bfr[nt] = *(const bf16x8_t*)&Bs[(row << 7) + (slot << 3)];
    }
#pragma unroll
    for (int nt = 0; nt < 8; nt++)
      acc[nt] = __builtin_amdgcn_mfma_f32_16x16x32_bf16(af, bfr[nt], acc[nt], 0, 0, 0);
  }
  __syncthreads();

  float bv[8];
#pragma unroll
  for (int nt = 0; nt < 8; nt++) bv[nt] = bias[(nt << 4) + r16];

  // C + bias -> As bf16 (stride 128), each wave its own 16 rows
#pragma unroll
  for (int reg = 0; reg < 4; reg++) {
    int lrow = mB + (q << 2) + reg;
#pragma unroll
    for (int nt = 0; nt < 8; nt++)
      As[(lrow << 7) + (nt << 4) + r16] = (short)f2bfbits(acc[nt][reg] + bv[nt]);
  }
  __syncthreads();
  // residual add (token-addressed), write x2, update LDS with x2
#pragma unroll
  for (int t = 0; t < 4; t++) {
    int f = tid + (t << 9);
    int row = f >> 4, c8 = (f & 15) << 3;
    int tt = winrev(rowBase + row);
    size_t ob = (size_t)tt * 128 + c8;
    float4 r0 = *(const float4*)(resX + ob);
    float4 r1 = *(const float4*)(resX + ob + 4);
    short* cs = &As[(row << 7) + c8];
    u16t pk[8];
    pk[0] = f2bfbits(sh2f(cs[0]) + r0.x); pk[1] = f2bfbits(sh2f(cs[1]) + r0.y);
    pk[2] = f2bfbits(sh2f(cs[2]) + r0.z); pk[3] = f2bfbits(sh2f(cs[3]) + r0.w);
    pk[4] = f2bfbits(sh2f(cs[4]) + r1.x); pk[5] = f2bfbits(sh2f(cs[5]) + r1.y);
    pk[6] = f2bfbits(sh2f(cs[6]) + r1.z); pk[7] = f2bfbits(sh2f(cs[7]) + r1.w);
    *(uint4*)((u16t*)outB + ob) = *(const uint4*)pk;
    *(uint4*)cs = *(const uint4*)pk;
  }
  __syncthreads();
  // fused LN2: one wave per row, 16 rows/wave, coalesced u32 LDS reads
  const int c = lane << 1;
  float2 lw = *(const float2*)(lnw + c);
  float2 lb = *(const float2*)(lnb + c);
#pragma unroll 4
  for (int rr = 0; rr < 16; rr++) {
    int row = (wv << 4) + rr;
    u32t u = *(const u32t*)&As[(row << 7) + c];
    float x0 = bflo(u), x1 = bfhi(u);
    float s = x0 + x1, ss = x0 * x0 + x1 * x1;
#pragma unroll
    for (int m = 32; m; m >>= 1) { s += __shfl_xor(s, m); ss += __shfl_xor(ss, m); }
    float mean = s * 0.0078125f;
    float var = ss * 0.0078125f - mean * mean;
    float rstd = rsqrtf(var + 1e-5f);
    float y0 = (x0 - mean) * rstd * lw.x + lb.x;
    float y1 = (x1 - mean) * rstd * lw.y + lb.y;
    int tt = winrev(rowBase + row);
    u32t ov = ((u32t)f2bfbits(y1) << 16) | (u32t)f2bfbits(y0);
    *(u32t*)((u16t*)outB2 + (size_t)tt * 128 + c) = ov;
  }
}

// ---------------------------------------------------------------------------
// Fused MLP: out = x2 + (GELU(xn2 @ fc1_w^T + b1) @ fc2_w^T + b2), fp32 out.
// 512 threads (8 waves, one 16-row m-tile each). LDS 80KB -> 2 blocks/CU.
// ---------------------------------------------------------------------------
__global__ __launch_bounds__(512, 4) void mlp_fused_k(
    const bf16* __restrict__ Axn, const bf16* __restrict__ F1,
    const bf16* __restrict__ F2, const float* __restrict__ b1,
    const float* __restrict__ b2, const bf16* __restrict__ resB,
    float* __restrict__ out)
{
  __shared__ __align__(16) char smem[81920];
  short* As  = (short*)smem;             // [128][128] xn2 tile, 32KB
  short* F1s = (short*)(smem + 32768);   // [64][128] fc1 chunk, 16KB
  short* F2s = (short*)(smem + 49152);   // [128][64] fc2 chunk, 16KB
  short* Hs  = (short*)(smem + 65536);   // [128][64] H chunk,   16KB
  float* Cf  = (float*)smem;             // [128][132] fp32 epilogue (67.5KB)

  const int tid = threadIdx.x;
  const int rowBase = blockIdx.x << 7;
  const int wv = tid >> 6, lane = tid & 63;
  const int q = lane >> 4, r16 = lane & 15;
  const int mB = wv << 4;                // one 16-row m-tile per wave

#pragma unroll
  for (int t = 0; t < 4; t++) {
    int f = tid + (t << 9);
    int row = f >> 4, cs = (f & 15) ^ (row & 15);
    gl_lds16((const u16t*)Axn + (size_t)(rowBase + row) * 128 + (cs << 3),
             &As[f << 3]);
  }
#pragma unroll
  for (int t = 0; t < 2; t++) {
    int f = tid + (t << 9);
    int row = f >> 4, cs = (f & 15) ^ (row & 15);
    gl_lds16((const u16t*)F1 + (size_t)row * 128 + (cs << 3), &F1s[f << 3]);
  }
#pragma unroll
  for (int t = 0; t < 2; t++) {
    int f = tid + (t << 9);
    int row = f >> 3, cs = (f & 7) ^ (row & 7);
    gl_lds16((const u16t*)F2 + (size_t)row * 512 + (cs << 3), &F2s[f << 3]);
  }
  __syncthreads();

  f32x4_t oacc[8];
#pragma unroll
  for (int j = 0; j < 8; j++) oacc[j] = (f32x4_t){0.f, 0.f, 0.f, 0.f};

#pragma unroll 1
  for (int c = 0; c < 8; c++) {
    if (c > 0) {
#pragma unroll
      for (int t = 0; t < 2; t++) {
        int f = tid + (t << 9);
        int row = f >> 4, cs = (f & 15) ^ (row & 15);
        gl_lds16((const u16t*)F1 + (size_t)(c * 64 + row) * 128 + (cs << 3),
                 &F1s[f << 3]);
      }
#pragma unroll
      for (int t = 0; t < 2; t++) {
        int f = tid + (t << 9);
        int row = f >> 3, cs = (f & 7) ^ (row & 7);
        gl_lds16((const u16t*)F2 + (size_t)row * 512 + c * 64 + (cs << 3),
                 &F2s[f << 3]);
      }
      __syncthreads();
    }

    // fc1: H-chunk rows mB..mB+15 (K=128, 4 ks; 16 MFMA/wave)
    f32x4_t hacc[4];
#pragma unroll
    for (int j = 0; j < 4; j++) hacc[j] = (f32x4_t){0.f, 0.f, 0.f, 0.f};
#pragma unroll
    for (int ks = 0; ks < 4; ks++) {
      int rowA = mB + r16;
      int slotA = ((ks << 2) + q) ^ (rowA & 15);
      bf16x8_t af = *(const bf16x8_t*)&As[(rowA << 7) + (slotA << 3)];
      bf16x8_t bfr[4];
#pragma unroll
      for (int nt = 0; nt < 4; nt++) {
        int row = (nt << 4) + r16;
        int slot = ((ks << 2) + q) ^ (row & 15);
        bfr[nt] = *(const bf16x8_t*)&F1s[(row << 7) + (slot << 3)];
      }
#pragma unroll
      for (int nt = 0; nt < 4; nt++)
        hacc[nt] = __builtin_amdgcn_mfma_f32_16x16x32_bf16(af, bfr[nt], hacc[nt], 0, 0, 0);
    }

    // bias + GELU -> Hs bf16 (8-short-slot XOR swizzle on row&7)
    float bb[4];
#pragma unroll
    for (int nt = 0; nt < 4; nt++) bb[nt] = b1[c * 64 + (nt << 4) + r16];
#pragma unroll
    for (int reg = 0; reg < 4; reg++) {
      int lrow = mB + (q << 2) + reg;
#pragma unroll
      for (int nt = 0; nt < 4; nt++) {
        float v = hacc[nt][reg] + bb[nt];
        v = 0.5f * v * (1.0f + erff(v * 0.70710678118654752f));
        int col = (nt << 4) + r16;
        int sp = (col >> 3) ^ (lrow & 7);
        Hs[(lrow << 6) + (sp << 3) + (col & 7)] = (short)f2bfbits(v);
      }
    }
    __syncthreads();

    // fc2: out += Hc @ F2c^T  (K=64, 2 ks; 16 MFMA/wave)
#pragma unroll
    for (int ks = 0; ks < 2; ks++) {
      int rowA = mB + r16;
      int slotA = ((ks << 2) + q) ^ (rowA & 7);
      bf16x8_t af = *(const bf16x8_t*)&Hs[(rowA << 6) + (slotA << 3)];
      bf16x8_t bfr[8];
#pragma unroll
      for (int nt = 0; nt < 8; nt++) {
        int row = (nt << 4) + r16;
        int slot = ((ks << 2) + q) ^ (row & 7);
        bfr[nt] = *(const bf16x8_t*)&F2s[(row << 6) + (slot << 3)];
      }
#pragma unroll
      for (int nt = 0; nt < 8; nt++)
        oacc[nt] = __builtin_amdgcn_mfma_f32_16x16x32_bf16(af, bfr[nt], oacc[nt], 0, 0, 0);
    }
    __syncthreads();   // guards next chunk's weight staging / Hs reuse
  }

  // epilogue: Cf = oacc + b2 (stride 132), coalesced float4 out + residual
  float bv[8];
#pragma unroll
  for (int nt = 0; nt < 8; nt++) bv[nt] = b2[(nt << 4) + r16];
#pragma unroll
  for (int reg = 0; reg < 4; reg++) {
    int lrow = mB + (q << 2) + reg;
#pragma unroll
    for (int nt = 0; nt < 8; nt++)
      Cf[lrow * 132 + (nt << 4) + r16] = oacc[nt][reg] + bv[nt];
  }
  __syncthreads();
#pragma unroll
  for (int t = 0; t < 8; t++) {
    int f = tid + (t << 9);
    int row = f >> 5, c4 = (f & 31) << 2;
    size_t ob = (size_t)(rowBase + row) * 128 + c4;
    const u16t* rp = (const u16t*)resB + ob;
    const float* cp = &Cf[row * 132 + c4];
    float4 v;
    v.x = cp[0] + sh2f(rp[0]);
    v.y = cp[1] + sh2f(rp[1]);
    v.z = cp[2] + sh2f(rp[2]);
    v.w = cp[3] + sh2f(rp[3]);
    *(float4*)(out + ob) = v;
  }
}

// ---------------------------------------------------------------------------
// MFMA windowed attention — latency-restructured: the QK^T phase (aq/bk/bias
// loads + MFMAs) is pure-register and softmax writes only the wave's OWN Ps
// rows (cols 0..111, byte-disjoint from the cross-thread pad cols 112..135),
// so both run BEFORE the barrier, overlapping the V-staging latency. Single
// barrier; post-barrier only PV (LDS reads) + stores. Identical arithmetic.
// ---------------------------------------------------------------------------
#define PSTR 136
__global__ __launch_bounds__(256) void attn_mfma_k(
    const bf16* __restrict__ qkv, const float* __restrict__ BmatT,
    bf16* __restrict__ out)
{
  __shared__ short Vt[32 * PSTR];    // V^T [d][j], zero-padded j>=98
  __shared__ short Ps[112 * PSTR];   // P [i][j] bf16, cols 112..135 zeroed
  const int nw = blockIdx.x, h = blockIdx.y;
  const int tid = threadIdx.x;
  const int wv = tid >> 6, lane = tid & 63;
  const int q = lane >> 4, r16 = lane & 15;

  // LDS zero fills (no global loads)
  for (int idx = tid; idx < 32 * 38; idx += 256) {
    int d = idx / 38, j = 98 + idx % 38;
    Vt[d * PSTR + j] = 0;
  }
  for (int idx = tid; idx < 112 * 12; idx += 256) {
    int r = idx / 12, c = (idx % 12) << 1;
    *(u32t*)&Ps[r * PSTR + 112 + c] = 0;
  }
  // V staging: global loads -> LDS transposed (latency overlapped below)
  for (int idx = tid; idx < NTOK * 16; idx += 256) {
    int j = idx >> 4, d2 = (idx & 15) << 1;
    u32t uv = *(const u32t*)((const u16t*)qkv +
                             (size_t)(nw * NTOK + j) * 384 + 256 + h * 32 + d2);
    Vt[d2 * PSTR + j] = (short)(uv & 0xffffu);
    Vt[(d2 + 1) * PSTR + j] = (short)(uv >> 16);
  }

  const int mt0 = wv;
  const bool has2 = (wv + 4) < 7;
  const int mt1 = has2 ? wv + 4 : wv;

  // ---- QK^T phase: pure-register, no LDS dependency (pre-barrier) ----
  int i0 = mt0 * 16 + r16; if (i0 > NTOK - 1) i0 = NTOK - 1;
  int i1 = mt1 * 16 + r16; if (i1 > NTOK - 1) i1 = NTOK - 1;
  bf16x8_t aq0 = *(const bf16x8_t*)((const u16t*)qkv +
      (size_t)(nw * NTOK + i0) * 384 + h * 32 + (q << 3));
  bf16x8_t aq1 = *(const bf16x8_t*)((const u16t*)qkv +
      (size_t)(nw * NTOK + i1) * 384 + h * 32 + (q << 3));

  f32x4_t sc[2][7];
#pragma unroll
  for (int nt = 0; nt < 7; nt++) {
    int j = (nt << 4) + r16; if (j > NTOK - 1) j = NTOK - 1;
    const float* bRow = &BmatT[(size_t)(h * NTOK + j) * 112];
    bf16x8_t bk = *(const bf16x8_t*)((const u16t*)qkv +
        (size_t)(nw * NTOK + j) * 384 + 128 + h * 32 + (q << 3));
    f32x4_t b0 = *(const f32x4_t*)&bRow[mt0 * 16 + (q << 2)];
    f32x4_t b1 = *(const f32x4_t*)&bRow[mt1 * 16 + (q << 2)];
    sc[0][nt] = __builtin_amdgcn_mfma_f32_16x16x32_bf16(aq0, bk, b0, 0, 0, 0);
    sc[1][nt] = __builtin_amdgcn_mfma_f32_16x16x32_bf16(aq1, bk, b1, 0, 0, 0);
  }

  // ---- softmax both sels -> Ps data writes (own-wave rows, cols 0..111;
  //      byte-disjoint from the pad-zero writes above) — still pre-barrier ----
#pragma unroll
  for (int sel = 0; sel < 2; sel++) {
    if (sel == 1 && !has2) break;
    int mtile = sel ? mt1 : mt0;
    int ibase = mtile * 16 + (q << 2);
    float s[4][7];
#pragma unroll
    for (int nt = 0; nt < 7; nt++) {
      int j = (nt << 4) + r16;
#pragma unroll
      for (int reg = 0; reg < 4; reg++) {
        int i = ibase + reg;
        s[reg][nt] = (i < NTOK && j < NTOK) ? sc[sel][nt][reg] : -1.0e30f;
      }
    }
#pragma unroll
    for (int reg = 0; reg < 4; reg++) {
      float m = -3.0e38f;
#pragma unroll
      for (int nt = 0; nt < 7; nt++) m = fmaxf(m, s[reg][nt]);
#pragma unroll
      for (int d = 8; d; d >>= 1) m = fmaxf(m, __shfl_xor(m, d));
      float sum = 0.f;
#pragma unroll
      for (int nt = 0; nt < 7; nt++) { s[reg][nt] = __expf(s[reg][nt] - m); sum += s[reg][nt]; }
#pragma unroll
      for (int d = 8; d; d >>= 1) sum += __shfl_xor(sum, d);
      float inv = 1.f / sum;
#pragma unroll
      for (int nt = 0; nt < 7; nt++)
        Ps[(ibase + reg) * PSTR + (nt << 4) + r16] =
            (short)f2bfbits(s[reg][nt] * inv);
    }
  }

  __syncthreads();   // single barrier: V staged + Ps data + pad zeros visible

  // ---- PV + stores (post-barrier) ----
#pragma unroll
  for (int sel = 0; sel < 2; sel++) {
    if (sel == 1 && !has2) break;
    int mtile = sel ? mt1 : mt0;
    f32x4_t o0 = {0.f, 0.f, 0.f, 0.f}, o1 = {0.f, 0.f, 0.f, 0.f};
#pragma unroll
    for (int kt = 0; kt < 4; kt++) {
      bf16x8_t ap = *(const bf16x8_t*)&Ps[(mtile * 16 + r16) * PSTR + (kt << 5) + (q << 3)];
      bf16x8_t bv0 = *(const bf16x8_t*)&Vt[r16 * PSTR + (kt << 5) + (q << 3)];
      bf16x8_t bv1 = *(const bf16x8_t*)&Vt[(16 + r16) * PSTR + (kt << 5) + (q << 3)];
      o0 = __builtin_amdgcn_mfma_f32_16x16x32_bf16(ap, bv0, o0, 0, 0, 0);
      o1 = __builtin_amdgcn_mfma_f32_16x16x32_bf16(ap, bv1, o1, 0, 0, 0);
    }
#pragma unroll
    for (int reg = 0; reg < 4; reg++) {
      int i = mtile * 16 + (q << 2) + reg;
      if (i < NTOK) {
        size_t ob = (size_t)(nw * NTOK + i) * 128 + h * 32;
        out[ob + r16] = f2bf(o0[reg]);
        out[ob + 16 + r16] = f2bf(o1[reg]);
      }
    }
  }
}

// ---------------------------------------------------------------------------
extern "C" void kernel_launch(void* const* d_in, const int* in_sizes, int n_in,
                              void* d_out, int out_size, void* d_ws, size_t ws_size,
                              hipStream_t stream) {
  const float* x      = (const float*)d_in[0];
  const float* n1w    = (const float*)d_in[1];
  const float* n1b    = (const float*)d_in[2];
  const float* qkv_w  = (const float*)d_in[3];
  const float* qkv_b  = (const float*)d_in[4];
  const float* btab   = (const float*)d_in[5];
  const float* proj_w = (const float*)d_in[6];
  const float* proj_b = (const float*)d_in[7];
  const float* n2w    = (const float*)d_in[8];
  const float* n2b    = (const float*)d_in[9];
  const float* fc1_w  = (const float*)d_in[10];
  const float* fc1_b  = (const float*)d_in[11];
  const float* fc2_w  = (const float*)d_in[12];
  const float* fc2_b  = (const float*)d_in[13];
  const int*   relidx = (const int*)d_in[14];

  // Layout (A = 50176*128*2 B = 12,845,056):
  //   ws[0,384K): bf16 weights; ws[384K,+176K): BmatT; then bscaled (1.5KB)
  //   R = ws+1MB: qkv [R,R+3A) -> x2 [R,R+A), xn2 [R+A,R+2A)
  //   d_out scratch: attn = d_out[0,A)
  const size_t Asz = (size_t)TOK * 128 * 2;
  char* ws = (char*)d_ws;
  bf16* wbf   = (bf16*)ws;
  bf16* qkvw16  = wbf;               // 49152
  bf16* projw16 = wbf + 49152;       // 16384
  bf16* fc1w16  = wbf + 65536;       // 65536
  bf16* fc2w16  = wbf + 131072;      // 65536
  float* BmatT = (float*)(ws + 393216);            // 4*98*112 fp32 = 175,616 B
  float* bsc   = (float*)(ws + 393216 + 175616);   // 384 fp32
  char* R = ws + (1 << 20);
  bf16* attn  = (bf16*)d_out;
  bf16* qkv   = (bf16*)R;
  bf16* x2    = (bf16*)R;
  bf16* xn2   = (bf16*)(R + Asz);
  float* out  = (float*)d_out;

  // 0. weight conversion (q pre-scaled) + bias matrix + scaled qkv bias
  setup_k<<<806, 256, 0, stream>>>(qkv_w, proj_w, fc1_w, fc2_w, wbf,
                                   btab, relidx, qkv_b, BmatT, bsc);
  // 1+2. fused LN1 + window partition + QKV GEMM (512 thr, 392 blocks)
  qkvln_k<<<TOK / 128, 512, 0, stream>>>(x, n1w, n1b, qkvw16, bsc, qkv);
  // 3. MFMA windowed attention (latency-restructured single-barrier)
  attn_mfma_k<<<dim3(NWIN, NHEAD), 256, 0, stream>>>(qkv, BmatT, attn);
  // 4. proj + window reverse + residual + fused LN2 -> x2, xn2 (512 thr)
  proj_k<<<TOK / 128, 512, 0, stream>>>(
      attn, projw16, proj_b, x, x2, xn2, n2w, n2b);
  // 5. fused MLP: fc1 + GELU + fc2 + residual, hmid stays in LDS (512 thr)
  mlp_fused_k<<<TOK / 128, 512, 0, stream>>>(
      xn2, fc1w16, fc2w16, fc1_b, fc2_b, x2, out);
}